// Round 13
// baseline (208.515 us; speedup 1.0000x reference)
//
#include <hip/hip_runtime.h>
#include <hip/hip_cooperative_groups.h>
#include <math.h>

#define B_    128
#define H_    192
#define W_    192
#define NC_   5
#define HW_   (H_*W_)
#define NPTS  9
#define EPS_  1e-8f
#define CHUNK 8                              // combos per warp task
#define MIXB  (B_*HW_/4/256)                 // 4608 mixup tasks
#define LOCB  ((W_/64)*(H_/4)*(B_/CHUNK))    // 2304 warp tasks per transform
#define COOPB 512                            // 2 blocks/CU x 256 CUs

typedef int   vint4   __attribute__((ext_vector_type(4)));
typedef float vfloat4 __attribute__((ext_vector_type(4)));
typedef float vfloat2 __attribute__((ext_vector_type(2)));

struct LinvT { float m[12][NPTS]; };

// ---------------- prep body: point_elasticity + TPS solve for one batch ---------------
__device__ __forceinline__ void prep_body(
    const int* __restrict__ masks, const float* __restrict__ ng,
    const float* __restrict__ nl, const LinvT& Linv, float* __restrict__ wts, int b)
{
    const float ETAB[5] = {0.05f, 0.12f, 0.08f, 0.15f, 0.1f};
    __shared__ int   sums[NPTS][NC_];
    __shared__ float elas_s[NPTS];
    int t = threadIdx.x;

    if (t < NPTS * NC_) {
        int pt = t / NC_, c = t - pt * NC_;
        int i = pt / 3, j = pt % 3;
        int yc = (i * (H_ - 1)) / 2;
        int xc = (j * (W_ - 1)) / 2;
        int y0 = yc - 2 < 0 ? 0 : yc - 2;
        int y1 = yc + 3 > H_ ? H_ : yc + 3;
        int x0 = xc - 2 < 0 ? 0 : xc - 2;
        int x1 = xc + 3 > W_ ? W_ : xc + 3;
        int s = 0;
        for (int y = y0; y < y1; ++y)
            for (int xx = x0; xx < x1; ++xx)
                s += masks[((size_t)b * NC_ + c) * HW_ + y * W_ + xx];
        sums[pt][c] = s;
    }
    __syncthreads();
    if (t < NPTS) {
        int best = -1, best_c = 0;
        #pragma unroll
        for (int c = 0; c < NC_; ++c) {
            int s = sums[t][c];
            if (s > best) { best = s; best_c = c; }  // strict >: first max (jnp.argmax)
        }
        elas_s[t] = ETAB[best_c];
    }
    __syncthreads();
    if (t < 24) {
        int tr = t / 12, r = t - tr * 12;       // tr=0 -> global (noise_g), 1 -> local
        const float* noise = (tr == 0) ? ng : nl;
        float disp[NPTS][2];
        #pragma unroll
        for (int k = 0; k < NPTS; ++k) {
            float e = elas_s[k];
            disp[k][0] = noise[((size_t)b * NPTS + k) * 2 + 0] * e;
            disp[k][1] = noise[((size_t)b * NPTS + k) * 2 + 1] * e;
        }
        #pragma unroll
        for (int c = 0; c < 2; ++c) {
            float nb = (disp[1][c] + disp[7][c] + disp[3][c] + disp[5][c]) * 0.25f;
            disp[4][c] = 0.8f * disp[4][c] + 0.2f * nb;
        }
        float a0 = 0.f, a1 = 0.f;
        #pragma unroll
        for (int k = 0; k < NPTS; ++k) {
            float d0 = (float)(k / 3 - 1) + disp[k][0];
            float d1 = (float)(k % 3 - 1) + disp[k][1];
            a0 += Linv.m[r][k] * d0;
            a1 += Linv.m[r][k] * d1;
        }
        float* wout = wts + ((size_t)tr * B_ + b) * 24;
        wout[r * 2 + 0] = a0;
        wout[r * 2 + 1] = a1;
    }
}

// ---------------- coordinate machinery (round-6 proven math) --------------------------
__device__ __forceinline__ void tps_coords_pk(
    const vfloat2* __restrict__ wt2, float px, float py, const float* __restrict__ u,
    int& o00, int& o01, int& o10, int& o11,
    float& w00, float& w01, float& w10, float& w11)
{
    vfloat2 g = wt2[9];
    g = __builtin_elementwise_fma((vfloat2){px, px}, wt2[10], g);
    g = __builtin_elementwise_fma((vfloat2){py, py}, wt2[11], g);
    #pragma unroll
    for (int k = 0; k < NPTS; ++k)
        g = __builtin_elementwise_fma((vfloat2){u[k], u[k]}, wt2[k], g);
    const float sc = 0.5f * (float)(W_ - 1);
    float ix = fmaf(g.x, sc, sc);
    float iy = fmaf(g.y, sc, sc);
    float x0f = floorf(ix), y0f = floorf(iy);
    float wx1 = ix - x0f, wx0 = 1.f - wx1;
    float wy1 = iy - y0f, wy0 = 1.f - wy1;
    int x0 = (int)x0f, y0 = (int)y0f;
    float fx0 = ((unsigned)x0 < 192u)       ? wx0 : 0.f;
    float fx1 = ((unsigned)(x0 + 1) < 192u) ? wx1 : 0.f;
    float fy0 = ((unsigned)y0 < 192u)       ? wy0 : 0.f;
    float fy1 = ((unsigned)(y0 + 1) < 192u) ? wy1 : 0.f;
    w00 = fy0 * fx0; w01 = fy0 * fx1; w10 = fy1 * fx0; w11 = fy1 * fx1;
    int o = y0 * W_ + x0;
    o00 = min(max(o, 0), HW_ - 1);
    o01 = min(max(o + 1, 0), HW_ - 1);
    o10 = min(max(o + W_, 0), HW_ - 1);
    o11 = min(max(o + W_ + 1, 0), HW_ - 1);
}

// 8 combos (one transform) for a 64x4 pixel tile; srcb = x (local) or mixed (global)
__device__ __forceinline__ void warp_body(
    const float* __restrict__ srcb, const float* __restrict__ wts,
    float* __restrict__ out, int gx, int gy, int combo0)
{
    int tx  = threadIdx.x;
    int wpx = gx * 64 + (tx & 63);
    int h   = gy * 4 + (tx >> 6);
    int p   = h * W_ + wpx;
    float px = -1.f + wpx * (2.f / (float)(W_ - 1));
    float py = -1.f + h   * (2.f / (float)(H_ - 1));

    float u[NPTS];
    #pragma unroll
    for (int k = 0; k < NPTS; ++k) {
        float dx = px - (float)(k / 3 - 1);
        float dy = py - (float)(k % 3 - 1);
        float d2 = dx * dx + dy * dy;
        u[k] = 0.5f * d2 * __logf(d2 + EPS_);
    }

    const vfloat2* wt2base = reinterpret_cast<const vfloat2*>(wts);

    #pragma unroll
    for (int g4 = 0; g4 < CHUNK; g4 += 4) {
        int   o00[4], o01[4], o10[4], o11[4];
        float w00[4], w01[4], w10[4], w11[4];
        const float* src[4];
        #pragma unroll
        for (int q = 0; q < 4; ++q) {
            int combo = combo0 + g4 + q;            // block-uniform
            int b = combo & (B_ - 1);
            src[q] = srcb + (size_t)b * HW_;
            tps_coords_pk(wt2base + (size_t)combo * 12, px, py, u,
                          o00[q], o01[q], o10[q], o11[q],
                          w00[q], w01[q], w10[q], w11[q]);
        }
        float v00[4], v01[4], v10[4], v11[4];
        #pragma unroll
        for (int q = 0; q < 4; ++q) {
            v00[q] = src[q][o00[q]];
            v01[q] = src[q][o01[q]];
            v10[q] = src[q][o10[q]];
            v11[q] = src[q][o11[q]];
        }
        #pragma unroll
        for (int q = 0; q < 4; ++q) {
            int combo = combo0 + g4 + q;
            float val = w00[q] * v00[q] + w01[q] * v01[q] +
                        w10[q] * v10[q] + w11[q] * v11[q];
            __builtin_nontemporal_store(val, &out[(size_t)combo * HW_ + p]);
        }
    }
}

// ---------------- mixup task body: 256 threads, 4 px each; mb in [0, 4608) ------------
__device__ __forceinline__ void mixup_body(
    const float* __restrict__ x, const int* __restrict__ masks,
    float lam, const int* __restrict__ perm,
    float* __restrict__ mixed, int mb)
{
    int idx = mb * 256 + threadIdx.x;
    int b  = idx / (HW_ / 4);
    int p4 = (idx - b * (HW_ / 4)) * 4;
    const vfloat4 xv = *reinterpret_cast<const vfloat4*>(x + (size_t)b * HW_ + p4);
    int pb = perm[b];
    const vfloat4 xp = *reinterpret_cast<const vfloat4*>(x + (size_t)pb * HW_ + p4);

    vint4 ma[NC_];
    #pragma unroll
    for (int c = 0; c < NC_; ++c)
        ma[c] = __builtin_nontemporal_load(
            reinterpret_cast<const vint4*>(masks + ((size_t)b * NC_ + c) * HW_ + p4));
    vfloat4 outv;
    #pragma unroll
    for (int l = 0; l < 4; ++l) {
        int s = 0, fg = 0;
        #pragma unroll
        for (int c = 0; c < NC_; ++c) { int m = ma[c][l]; s += m; fg += (m == 1); }
        float bg = (s == 0) ? 1.f : 0.f;
        outv[l] = bg * xv[l] + (float)fg * (lam * xv[l] + (1.f - lam) * xp[l]);
    }
    *reinterpret_cast<vfloat4*>(mixed + (size_t)b * HW_ + p4) = outv;
}

// ---------------- fused cooperative kernel: prep | sync | mix∥local | sync | global ----
__global__ __launch_bounds__(256, 2) void fused_kernel(
    const float* __restrict__ x, const int* __restrict__ masks,
    const float* __restrict__ lam_p, const int* __restrict__ perm,
    const float* __restrict__ ng, const float* __restrict__ nl,
    LinvT Linv, float* __restrict__ wts, float* __restrict__ mixed,
    float* __restrict__ out)
{
    cooperative_groups::grid_group grid = cooperative_groups::this_grid();
    float lam = lam_p[0];

    // phase 0: prep (blocks 0..127)
    if (blockIdx.x < B_)
        prep_body(masks, ng, nl, Linv, wts, blockIdx.x);
    grid.sync();

    // phase A: mixup ∥ local-warp, 2:1 interleave, XCD-affinity for warp tasks
    for (int T = blockIdx.x; T < MIXB + LOCB; T += COOPB) {
        int group = T / 3;
        int r     = T - group * 3;
        if (r < 2) {
            mixup_body(x, masks, lam, perm, mixed, group * 2 + r);   // mb 0..4607
        } else {
            int lb   = group;                                        // 0..2303
            int half = (lb >= LOCB / 2) ? 1 : 0;
            int lbh  = lb - half * (LOCB / 2);
            int gz   = (lbh & 7) + 8 * half;                         // [0,16)
            int inner = lbh >> 3;                                    // [0,144)
            warp_body(x, wts, out, inner % 3, inner / 3, B_ + gz * CHUNK);
        }
    }
    grid.sync();

    // phase B: global-warp (needs completed mixed); gz = T&15 -> XCD-affine
    for (int T = blockIdx.x; T < LOCB; T += COOPB) {
        int gz    = T & 15;
        int inner = T >> 4;
        warp_body(mixed, wts, out, inner % 3, inner / 3, gz * CHUNK);
    }
}

// ---------------- fallback path: round-12 three-kernel pipeline ------------------------
__global__ void prep_kernel(const int* __restrict__ masks,
                            const float* __restrict__ ng,
                            const float* __restrict__ nl,
                            LinvT Linv, float* __restrict__ wts)
{
    prep_body(masks, ng, nl, Linv, wts, blockIdx.x);
}

__global__ __launch_bounds__(256, 2) void mix_local_kernel(
    const float* __restrict__ x, const int* __restrict__ masks,
    const float* __restrict__ lam_p, const int* __restrict__ perm,
    float* __restrict__ mixed, const float* __restrict__ wts,
    float* __restrict__ out)
{
    int bid   = blockIdx.x;
    int group = bid / 3;
    int r     = bid - group * 3;
    if (r < 2) {
        mixup_body(x, masks, lam_p[0], perm, mixed, group * 2 + r);
    } else {
        int lb   = group;
        int half = (lb >= LOCB / 2) ? 1 : 0;
        int lbh  = lb - half * (LOCB / 2);
        int gz   = (lbh & 7) + 8 * half;
        int inner = lbh >> 3;
        warp_body(x, wts, out, inner % 3, inner / 3, B_ + gz * CHUNK);
    }
}

__global__ __launch_bounds__(256, 2) void warp_global_kernel(
    const float* __restrict__ mixed, const float* __restrict__ wts,
    float* __restrict__ out)
{
    int gz    = blockIdx.x & 15;
    int inner = blockIdx.x >> 4;
    warp_body(mixed, wts, out, inner % 3, inner / 3, gz * CHUNK);
}

// ---------------- Host: build constant L^-1 (first 9 columns) in double ----------------
static void build_linv(LinvT* out)
{
    double srcp[NPTS][2];
    for (int k = 0; k < NPTS; ++k) {
        srcp[k][0] = (double)(k / 3) - 1.0;
        srcp[k][1] = (double)(k % 3) - 1.0;
    }
    double A[12][24];
    for (int r = 0; r < 12; ++r)
        for (int c = 0; c < 24; ++c) A[r][c] = 0.0;
    for (int i = 0; i < NPTS; ++i) {
        for (int j = 0; j < NPTS; ++j) {
            double dx = srcp[i][0] - srcp[j][0];
            double dy = srcp[i][1] - srcp[j][1];
            double d2 = dx * dx + dy * dy;
            A[i][j] = 0.5 * d2 * log(d2 + 1e-8);
        }
        A[i][9]  = 1.0; A[i][10] = srcp[i][0]; A[i][11] = srcp[i][1];
        A[9][i]  = 1.0; A[10][i] = srcp[i][0]; A[11][i] = srcp[i][1];
    }
    for (int r = 0; r < 12; ++r) A[r][12 + r] = 1.0;
    for (int col = 0; col < 12; ++col) {
        int piv = col; double mx = fabs(A[col][col]);
        for (int r = col + 1; r < 12; ++r)
            if (fabs(A[r][col]) > mx) { mx = fabs(A[r][col]); piv = r; }
        if (piv != col)
            for (int c = 0; c < 24; ++c) { double tmp = A[col][c]; A[col][c] = A[piv][c]; A[piv][c] = tmp; }
        double d = A[col][col];
        for (int c = 0; c < 24; ++c) A[col][c] /= d;
        for (int r = 0; r < 12; ++r) {
            if (r == col) continue;
            double f = A[r][col];
            if (f != 0.0)
                for (int c = 0; c < 24; ++c) A[r][c] -= f * A[col][c];
        }
    }
    for (int r = 0; r < 12; ++r)
        for (int k = 0; k < NPTS; ++k)
            out->m[r][k] = (float)A[r][12 + k];
}

extern "C" void kernel_launch(void* const* d_in, const int* in_sizes, int n_in,
                              void* d_out, int out_size, void* d_ws, size_t ws_size,
                              hipStream_t stream)
{
    (void)in_sizes; (void)n_in; (void)out_size; (void)ws_size;
    const float* x     = (const float*)d_in[0];
    const int*   masks = (const int*)d_in[1];
    const float* lam   = (const float*)d_in[2];
    const int*   perm  = (const int*)d_in[3];
    const float* ng    = (const float*)d_in[4];
    const float* nl    = (const float*)d_in[5];
    float* out = (float*)d_out;

    char* ws = (char*)d_ws;
    float* wts   = (float*)ws;              // 2*128*24*4 = 24576 B
    float* mixed = (float*)(ws + 32768);    // B*HW*4    = 18.9 MB

    LinvT Linv;
    build_linv(&Linv);

    void* args[] = {(void*)&x, (void*)&masks, (void*)&lam, (void*)&perm,
                    (void*)&ng, (void*)&nl, (void*)&Linv, (void*)&wts,
                    (void*)&mixed, (void*)&out};
    hipError_t err = hipLaunchCooperativeKernel(
        (const void*)fused_kernel, dim3(COOPB), dim3(256), args, 0, stream);

    if (err != hipSuccess) {
        // deterministic fallback: round-12 three-kernel pipeline
        prep_kernel<<<B_, 64, 0, stream>>>(masks, ng, nl, Linv, wts);
        mix_local_kernel<<<MIXB + LOCB, 256, 0, stream>>>(
            x, masks, lam, perm, mixed, wts, out);
        warp_global_kernel<<<LOCB, 256, 0, stream>>>(mixed, wts, out);
    }
}

// Round 14
// 56.872 us; speedup vs baseline: 3.6664x; 3.6664x over previous
//
#include <hip/hip_runtime.h>
#include <math.h>

#define B_    128
#define H_    192
#define W_    192
#define NC_   5
#define HW_   (H_*W_)
#define NPTS  9
#define EPS_  1e-8f
#define CHUNK 8                              // combos per warp block
#define MIXB  (B_*HW_/4/256)                 // 4608 mixup blocks
#define LOCB  ((W_/64)*(H_/4)*(B_/CHUNK))    // 3*48*16 = 2304 local-warp blocks

typedef int   vint4   __attribute__((ext_vector_type(4)));
typedef float vfloat4 __attribute__((ext_vector_type(4)));
typedef float vfloat2 __attribute__((ext_vector_type(2)));

struct LinvT { float m[12][NPTS]; };

// ---------------- prep: point_elasticity + TPS solve fused (per-batch block) ----------
__global__ void prep_kernel(const int* __restrict__ masks,
                            const float* __restrict__ ng,
                            const float* __restrict__ nl,
                            LinvT Linv, float* __restrict__ wts)
{
    const float ETAB[5] = {0.05f, 0.12f, 0.08f, 0.15f, 0.1f};
    __shared__ int   sums[NPTS][NC_];
    __shared__ float elas_s[NPTS];
    int b = blockIdx.x;
    int t = threadIdx.x;

    if (t < NPTS * NC_) {
        int pt = t / NC_, c = t - pt * NC_;
        int i = pt / 3, j = pt % 3;
        int yc = (i * (H_ - 1)) / 2;
        int xc = (j * (W_ - 1)) / 2;
        int y0 = yc - 2 < 0 ? 0 : yc - 2;
        int y1 = yc + 3 > H_ ? H_ : yc + 3;
        int x0 = xc - 2 < 0 ? 0 : xc - 2;
        int x1 = xc + 3 > W_ ? W_ : xc + 3;
        int s = 0;
        for (int y = y0; y < y1; ++y)
            for (int xx = x0; xx < x1; ++xx)
                s += masks[((size_t)b * NC_ + c) * HW_ + y * W_ + xx];
        sums[pt][c] = s;
    }
    __syncthreads();
    if (t < NPTS) {
        int best = -1, best_c = 0;
        #pragma unroll
        for (int c = 0; c < NC_; ++c) {
            int s = sums[t][c];
            if (s > best) { best = s; best_c = c; }  // strict >: first max (jnp.argmax)
        }
        elas_s[t] = ETAB[best_c];
    }
    __syncthreads();
    if (t < 24) {
        int tr = t / 12, r = t - tr * 12;       // tr=0 -> global (noise_g), 1 -> local
        const float* noise = (tr == 0) ? ng : nl;
        float disp[NPTS][2];
        #pragma unroll
        for (int k = 0; k < NPTS; ++k) {
            float e = elas_s[k];
            disp[k][0] = noise[((size_t)b * NPTS + k) * 2 + 0] * e;
            disp[k][1] = noise[((size_t)b * NPTS + k) * 2 + 1] * e;
        }
        #pragma unroll
        for (int c = 0; c < 2; ++c) {
            float nb = (disp[1][c] + disp[7][c] + disp[3][c] + disp[5][c]) * 0.25f;
            disp[4][c] = 0.8f * disp[4][c] + 0.2f * nb;
        }
        float a0 = 0.f, a1 = 0.f;
        #pragma unroll
        for (int k = 0; k < NPTS; ++k) {
            float d0 = (float)(k / 3 - 1) + disp[k][0];
            float d1 = (float)(k % 3 - 1) + disp[k][1];
            a0 += Linv.m[r][k] * d0;
            a1 += Linv.m[r][k] * d1;
        }
        float* wout = wts + ((size_t)tr * B_ + b) * 24;
        wout[r * 2 + 0] = a0;
        wout[r * 2 + 1] = a1;
    }
}

// ---------------- coordinate machinery (round-6 proven math) --------------------------
__device__ __forceinline__ void tps_coords_pk(
    const vfloat2* __restrict__ wt2, float px, float py, const float* __restrict__ u,
    int& o00, int& o01, int& o10, int& o11,
    float& w00, float& w01, float& w10, float& w11)
{
    vfloat2 g = wt2[9];
    g = __builtin_elementwise_fma((vfloat2){px, px}, wt2[10], g);
    g = __builtin_elementwise_fma((vfloat2){py, py}, wt2[11], g);
    #pragma unroll
    for (int k = 0; k < NPTS; ++k)
        g = __builtin_elementwise_fma((vfloat2){u[k], u[k]}, wt2[k], g);
    const float sc = 0.5f * (float)(W_ - 1);
    float ix = fmaf(g.x, sc, sc);
    float iy = fmaf(g.y, sc, sc);
    float x0f = floorf(ix), y0f = floorf(iy);
    float wx1 = ix - x0f, wx0 = 1.f - wx1;
    float wy1 = iy - y0f, wy0 = 1.f - wy1;
    int x0 = (int)x0f, y0 = (int)y0f;
    float fx0 = ((unsigned)x0 < 192u)       ? wx0 : 0.f;
    float fx1 = ((unsigned)(x0 + 1) < 192u) ? wx1 : 0.f;
    float fy0 = ((unsigned)y0 < 192u)       ? wy0 : 0.f;
    float fy1 = ((unsigned)(y0 + 1) < 192u) ? wy1 : 0.f;
    w00 = fy0 * fx0; w01 = fy0 * fx1; w10 = fy1 * fx0; w11 = fy1 * fx1;
    int o = y0 * W_ + x0;
    o00 = min(max(o, 0), HW_ - 1);
    o01 = min(max(o + 1, 0), HW_ - 1);
    o10 = min(max(o + W_, 0), HW_ - 1);
    o11 = min(max(o + W_ + 1, 0), HW_ - 1);
}

// 8 combos (one transform) for a 64x4 pixel tile; srcb = x (local) or mixed (global)
// Round-8 proven form: 2 subgroups of 4 combos.
__device__ __forceinline__ void warp_body(
    const float* __restrict__ srcb, const float* __restrict__ wts,
    float* __restrict__ out, int gx, int gy, int combo0)
{
    int tx  = threadIdx.x;
    int wpx = gx * 64 + (tx & 63);
    int h   = gy * 4 + (tx >> 6);
    int p   = h * W_ + wpx;
    float px = -1.f + wpx * (2.f / (float)(W_ - 1));
    float py = -1.f + h   * (2.f / (float)(H_ - 1));

    float u[NPTS];
    #pragma unroll
    for (int k = 0; k < NPTS; ++k) {
        float dx = px - (float)(k / 3 - 1);
        float dy = py - (float)(k % 3 - 1);
        float d2 = dx * dx + dy * dy;
        u[k] = 0.5f * d2 * __logf(d2 + EPS_);
    }

    const vfloat2* wt2base = reinterpret_cast<const vfloat2*>(wts);

    #pragma unroll
    for (int g4 = 0; g4 < CHUNK; g4 += 4) {
        int   o00[4], o01[4], o10[4], o11[4];
        float w00[4], w01[4], w10[4], w11[4];
        const float* src[4];
        #pragma unroll
        for (int q = 0; q < 4; ++q) {
            int combo = combo0 + g4 + q;            // block-uniform
            int b = combo & (B_ - 1);
            src[q] = srcb + (size_t)b * HW_;
            tps_coords_pk(wt2base + (size_t)combo * 12, px, py, u,
                          o00[q], o01[q], o10[q], o11[q],
                          w00[q], w01[q], w10[q], w11[q]);
        }
        float v00[4], v01[4], v10[4], v11[4];
        #pragma unroll
        for (int q = 0; q < 4; ++q) {
            v00[q] = src[q][o00[q]];
            v01[q] = src[q][o01[q]];
            v10[q] = src[q][o10[q]];
            v11[q] = src[q][o11[q]];
        }
        #pragma unroll
        for (int q = 0; q < 4; ++q) {
            int combo = combo0 + g4 + q;
            float val = w00[q] * v00[q] + w01[q] * v01[q] +
                        w10[q] * v10[q] + w11[q] * v11[q];
            __builtin_nontemporal_store(val, &out[(size_t)combo * HW_ + p]);
        }
    }
}

// ---------------- mixup block body: 256 threads, 4 px each; mb in [0, 4608) -----------
__device__ __forceinline__ void mixup_body(
    const float* __restrict__ x, const int* __restrict__ masks,
    const float* __restrict__ lam_p, const int* __restrict__ perm,
    float* __restrict__ mixed, int mb)
{
    int idx = mb * 256 + threadIdx.x;
    float lam = lam_p[0];
    int b  = idx / (HW_ / 4);
    int p4 = (idx - b * (HW_ / 4)) * 4;
    const vfloat4 xv = *reinterpret_cast<const vfloat4*>(x + (size_t)b * HW_ + p4);
    int pb = perm[b];
    const vfloat4 xp = *reinterpret_cast<const vfloat4*>(x + (size_t)pb * HW_ + p4);

    vint4 ma[NC_];
    #pragma unroll
    for (int c = 0; c < NC_; ++c)
        ma[c] = __builtin_nontemporal_load(
            reinterpret_cast<const vint4*>(masks + ((size_t)b * NC_ + c) * HW_ + p4));
    vfloat4 outv;
    #pragma unroll
    for (int l = 0; l < 4; ++l) {
        int s = 0, fg = 0;
        #pragma unroll
        for (int c = 0; c < NC_; ++c) { int m = ma[c][l]; s += m; fg += (m == 1); }
        float bg = (s == 0) ? 1.f : 0.f;
        outv[l] = bg * xv[l] + (float)fg * (lam * xv[l] + (1.f - lam) * xp[l]);
    }
    *reinterpret_cast<vfloat4*>(mixed + (size_t)b * HW_ + p4) = outv;
}

// ---------------- K2: heterogeneous grid — mixup blocks + local-warp blocks -----------
// 2 mixup : 1 local-warp interleave. Local-warp blocks get XCD-affinity: all blocks
// sharing a gz (8 images, 1.2 MB) have lb ≡ gz (mod 8), so with the 3-stride inside
// the grid they land on one XCD class -> image tiles stay L2-resident. (Perf-only.)
__global__ __launch_bounds__(256, 2) void mix_local_kernel(
    const float* __restrict__ x, const int* __restrict__ masks,
    const float* __restrict__ lam_p, const int* __restrict__ perm,
    float* __restrict__ mixed, const float* __restrict__ wts,
    float* __restrict__ out)
{
    int bid   = blockIdx.x;           // total = MIXB + LOCB = 6912 (MIXB = 2*LOCB)
    int group = bid / 3;
    int r     = bid - group * 3;

    if (r < 2) {
        mixup_body(x, masks, lam_p, perm, mixed, group * 2 + r);   // mb 0..4607
    } else {
        int lb = group;                                            // 0..2303
        // XCD-affinity decode: gz = (lb&7) [+8 for second half], inner = lb>>3
        int half  = (lb >= LOCB / 2) ? 1 : 0;
        int lbh   = lb - half * (LOCB / 2);                        // 0..1151
        int gz    = (lbh & 7) + 8 * half;                          // [0,16)
        int inner = lbh >> 3;                                      // [0,144)
        int gx = inner % 3, gy = inner / 3;
        warp_body(x, wts, out, gx, gy, B_ + gz * CHUNK);           // local combos 128..255
    }
}

// ---------------- K3: global-transform warp (needs completed mixed) -------------------
// 1-D grid of 2304; gz = bid&15 -> bid%8 = gz%8 constant per gz -> one XCD per gz.
__global__ __launch_bounds__(256, 2) void warp_global_kernel(
    const float* __restrict__ mixed, const float* __restrict__ wts,
    float* __restrict__ out)
{
    int bid   = blockIdx.x;
    int gz    = bid & 15;                                          // [0,16)
    int inner = bid >> 4;                                          // [0,144)
    int gx = inner % 3, gy = inner / 3;
    warp_body(mixed, wts, out, gx, gy, gz * CHUNK);                // combos 0..127
}

// ---------------- Host: build constant L^-1 (first 9 columns) in double ----------------
static void build_linv(LinvT* out)
{
    double srcp[NPTS][2];
    for (int k = 0; k < NPTS; ++k) {
        srcp[k][0] = (double)(k / 3) - 1.0;
        srcp[k][1] = (double)(k % 3) - 1.0;
    }
    double A[12][24];
    for (int r = 0; r < 12; ++r)
        for (int c = 0; c < 24; ++c) A[r][c] = 0.0;
    for (int i = 0; i < NPTS; ++i) {
        for (int j = 0; j < NPTS; ++j) {
            double dx = srcp[i][0] - srcp[j][0];
            double dy = srcp[i][1] - srcp[j][1];
            double d2 = dx * dx + dy * dy;
            A[i][j] = 0.5 * d2 * log(d2 + 1e-8);
        }
        A[i][9]  = 1.0; A[i][10] = srcp[i][0]; A[i][11] = srcp[i][1];
        A[9][i]  = 1.0; A[10][i] = srcp[i][0]; A[11][i] = srcp[i][1];
    }
    for (int r = 0; r < 12; ++r) A[r][12 + r] = 1.0;
    for (int col = 0; col < 12; ++col) {
        int piv = col; double mx = fabs(A[col][col]);
        for (int r = col + 1; r < 12; ++r)
            if (fabs(A[r][col]) > mx) { mx = fabs(A[r][col]); piv = r; }
        if (piv != col)
            for (int c = 0; c < 24; ++c) { double tmp = A[col][c]; A[col][c] = A[piv][c]; A[piv][c] = tmp; }
        double d = A[col][col];
        for (int c = 0; c < 24; ++c) A[col][c] /= d;
        for (int r = 0; r < 12; ++r) {
            if (r == col) continue;
            double f = A[r][col];
            if (f != 0.0)
                for (int c = 0; c < 24; ++c) A[r][c] -= f * A[col][c];
        }
    }
    for (int r = 0; r < 12; ++r)
        for (int k = 0; k < NPTS; ++k)
            out->m[r][k] = (float)A[r][12 + k];
}

extern "C" void kernel_launch(void* const* d_in, const int* in_sizes, int n_in,
                              void* d_out, int out_size, void* d_ws, size_t ws_size,
                              hipStream_t stream)
{
    (void)in_sizes; (void)n_in; (void)out_size; (void)ws_size;
    const float* x     = (const float*)d_in[0];
    const int*   masks = (const int*)d_in[1];
    const float* lam   = (const float*)d_in[2];
    const int*   perm  = (const int*)d_in[3];
    const float* ng    = (const float*)d_in[4];
    const float* nl    = (const float*)d_in[5];
    float* out = (float*)d_out;

    char* ws = (char*)d_ws;
    float* wts   = (float*)ws;              // 2*128*24*4 = 24576 B
    float* mixed = (float*)(ws + 32768);    // B*HW*4    = 18.9 MB

    LinvT Linv;
    build_linv(&Linv);

    prep_kernel<<<B_, 64, 0, stream>>>(masks, ng, nl, Linv, wts);
    mix_local_kernel<<<MIXB + LOCB, 256, 0, stream>>>(
        x, masks, lam, perm, mixed, wts, out);
    warp_global_kernel<<<LOCB, 256, 0, stream>>>(mixed, wts, out);
}